// Round 4
// baseline (385.899 us; speedup 1.0000x reference)
//
#include <hip/hip_runtime.h>

typedef unsigned short u16;
typedef unsigned int u32;
typedef __bf16 bf16x8 __attribute__((ext_vector_type(8)));
typedef float f32x4 __attribute__((ext_vector_type(4)));

__device__ __forceinline__ u16 f2b(float f) {
  u32 u = __float_as_uint(f);
  u32 r = (u + 0x7fffu + ((u >> 16) & 1u)) >> 16;
  return (u16)r;
}
__device__ __forceinline__ float b2f(u16 v) {
  return __uint_as_float(((u32)v) << 16);
}

// ---------------- fused fp32 -> bf16 cast of query, W_qkv, W_out ----------------
__global__ __launch_bounds__(256) void convert_all(
    const float4* __restrict__ q, const float4* __restrict__ w1,
    const float4* __restrict__ w2, ushort4* __restrict__ out) {
  int i = blockIdx.x * 256 + threadIdx.x;  // < 6291456
  float4 f;
  if (i < 2097152) f = q[i];
  else if (i < 5242880) f = w1[i - 2097152];
  else f = w2[i - 5242880];
  ushort4 o;
  o.x = f2b(f.x); o.y = f2b(f.y); o.z = f2b(f.z); o.w = f2b(f.w);
  out[i] = o;
}

// ---------------- RoPE cos/sin table: tab[l*64+dp] = (cos, sin) ----------------
__global__ __launch_bounds__(256) void rope_tab(float2* __restrict__ tab) {
  int idx = blockIdx.x * 256 + threadIdx.x;  // 131072 = 2048*64
  int l = idx >> 6, dp = idx & 63;
  float inv = exp2f(-(float)dp * 0.20762050593046869f);  // log2(10000)/64
  float ang = (float)l * inv;
  float s, c;
  sincosf(ang, &s, &c);
  tab[idx] = make_float2(c, s);
}

// ---------------- GEMM1 + fused RoPE/head-split/V-transpose epilogue ----------
// Round-0 known-good structure (141 us, 730 TF): 128x128 tile, 4 blocks/CU TLP.
__global__ __launch_bounds__(256) void gemm_qkv(
    const u16* __restrict__ A, const u16* __restrict__ B,
    const float* __restrict__ bias, const float2* __restrict__ tab,
    u16* __restrict__ qh, u16* __restrict__ kh, u16* __restrict__ vhT) {
  __shared__ __align__(16) u16 sh[16512];  // As(8192) | Bs(8192); epi: T stride 129
  u16* As = sh;
  u16* Bs = sh + 8192;
  const int K = 2048;
  const int tid = threadIdx.x;
  const int lane = tid & 63;
  const int wave = tid >> 6;
  const int m0 = blockIdx.y * 128;
  const int n0 = blockIdx.x * 128;
  const int wm = (wave & 1) * 64;
  const int wn = (wave >> 1) * 64;
  f32x4 acc[4][4] = {};

  const int srow = wave * 32 + (lane >> 3);
  const int scb = ((lane & 7) ^ (lane >> 3)) * 16;
  const int fr = lane & 15;
  const int g = lane >> 4;

  for (int kt = 0; kt < 32; ++kt) {
    const int k0 = kt << 6;
    __syncthreads();
    {
      const char* gA = (const char*)A + ((size_t)(m0 + srow) * K + k0) * 2 + scb;
      const char* gB = (const char*)B + ((size_t)(n0 + srow) * K + k0) * 2 + scb;
#pragma unroll
      for (int i = 0; i < 4; ++i) {
        __builtin_amdgcn_global_load_lds(
            (__attribute__((address_space(1))) void*)(gA + (size_t)i * 8 * K * 2),
            (__attribute__((address_space(3))) void*)(As + (wave * 32 + i * 8) * 64),
            16, 0, 0);
        __builtin_amdgcn_global_load_lds(
            (__attribute__((address_space(1))) void*)(gB + (size_t)i * 8 * K * 2),
            (__attribute__((address_space(3))) void*)(Bs + (wave * 32 + i * 8) * 64),
            16, 0, 0);
      }
    }
    __syncthreads();
#pragma unroll
    for (int ks = 0; ks < 2; ++ks) {
      const int so = ((ks * 4 + g) ^ (fr & 7)) * 8;
      bf16x8 aF[4], bF[4];
#pragma unroll
      for (int mi = 0; mi < 4; ++mi)
        __builtin_memcpy(&aF[mi], &As[(wm + mi * 16 + fr) * 64 + so], 16);
#pragma unroll
      for (int ni = 0; ni < 4; ++ni)
        __builtin_memcpy(&bF[ni], &Bs[(wn + ni * 16 + fr) * 64 + so], 16);
#pragma unroll
      for (int mi = 0; mi < 4; ++mi)
#pragma unroll
        for (int ni = 0; ni < 4; ++ni)
          acc[mi][ni] = __builtin_amdgcn_mfma_f32_16x16x32_bf16(aF[mi], bF[ni], acc[mi][ni], 0, 0, 0);
    }
  }

  // ---- epilogue: acc -> LDS tile T (bf16, stride 129) ----
  __syncthreads();  // all waves done reading As/Bs before overwrite
  const int rq = (lane >> 4) * 4;
  const int cq = lane & 15;
#pragma unroll
  for (int mi = 0; mi < 4; ++mi) {
#pragma unroll
    for (int ni = 0; ni < 4; ++ni) {
      int c = wn + ni * 16 + cq;
      float bs = bias[n0 + c];
#pragma unroll
      for (int i = 0; i < 4; ++i) {
        int r = wm + mi * 16 + rq + i;
        sh[r * 129 + c] = f2b(acc[mi][ni][i] + bs);
      }
    }
  }
  __syncthreads();

  const int t = n0 >> 7;       // 0..47
  const int h = t & 15;
  const int bq = m0 >> 11;     // batch (M = B*L, 2048 each)
  const int l0 = m0 & 2047;
  const int bh = bq * 16 + h;

  if (t < 32) {
    // q or k head tile: RoPE rows. 128 rows x 64 pairs, 32 iters.
    const float qs = (t < 16) ? 0.08838834764831845f : 1.0f;
    u16* dst = (t < 16) ? qh : kh;
#pragma unroll 4
    for (int it = 0; it < 32; ++it) {
      int idx = it * 256 + tid;
      int l = idx >> 6, dp = idx & 63;
      float2 cs = tab[(size_t)(l0 + l) * 64 + dp];
      float x1 = b2f(sh[l * 129 + dp]);
      float x2 = b2f(sh[l * 129 + dp + 64]);
      size_t o = ((size_t)bh * 2048 + l0 + l) * 128;
      dst[o + dp]      = f2b((x1 * cs.x - x2 * cs.y) * qs);
      dst[o + dp + 64] = f2b((x2 * cs.x + x1 * cs.y) * qs);
    }
  } else {
    // v head tile: transposed store vhT[bh*128+d][l]. 128 d x 64 l-pairs.
#pragma unroll 4
    for (int it = 0; it < 32; ++it) {
      int idx = it * 256 + tid;
      int d = idx >> 6, l2 = (idx & 63) * 2;
      ushort2 t2;
      t2.x = sh[l2 * 129 + d];
      t2.y = sh[(l2 + 1) * 129 + d];
      *(ushort2*)(vhT + ((size_t)bh * 128 + d) * 2048 + l0 + l2) = t2;
    }
  }
}

// ---------------- GEMM2: out[M,N] = A[M,K] * B[N,K]^T + bias (fp32 out) -------
__global__ __launch_bounds__(256) void gemm_bt(
    const u16* __restrict__ A, const u16* __restrict__ B,
    const float* __restrict__ bias, float* __restrict__ C,
    int M, int N, int K) {
  __shared__ __align__(16) u16 As[128 * 64];
  __shared__ __align__(16) u16 Bs[128 * 64];
  const int tid = threadIdx.x;
  const int lane = tid & 63;
  const int wave = tid >> 6;
  const int m0 = blockIdx.y * 128;
  const int n0 = blockIdx.x * 128;
  const int wm = (wave & 1) * 64;
  const int wn = (wave >> 1) * 64;
  f32x4 acc[4][4] = {};

  const int srow = wave * 32 + (lane >> 3);
  const int scb = ((lane & 7) ^ (lane >> 3)) * 16;
  const int fr = lane & 15;
  const int g = lane >> 4;

  const int kiters = K >> 6;
  for (int kt = 0; kt < kiters; ++kt) {
    const int k0 = kt << 6;
    __syncthreads();
    {
      const char* gA = (const char*)A + ((size_t)(m0 + srow) * K + k0) * 2 + scb;
      const char* gB = (const char*)B + ((size_t)(n0 + srow) * K + k0) * 2 + scb;
#pragma unroll
      for (int i = 0; i < 4; ++i) {
        __builtin_amdgcn_global_load_lds(
            (__attribute__((address_space(1))) void*)(gA + (size_t)i * 8 * K * 2),
            (__attribute__((address_space(3))) void*)(As + (wave * 32 + i * 8) * 64),
            16, 0, 0);
        __builtin_amdgcn_global_load_lds(
            (__attribute__((address_space(1))) void*)(gB + (size_t)i * 8 * K * 2),
            (__attribute__((address_space(3))) void*)(Bs + (wave * 32 + i * 8) * 64),
            16, 0, 0);
      }
    }
    __syncthreads();
#pragma unroll
    for (int ks = 0; ks < 2; ++ks) {
      const int so = ((ks * 4 + g) ^ (fr & 7)) * 8;
      bf16x8 aF[4], bF[4];
#pragma unroll
      for (int mi = 0; mi < 4; ++mi)
        __builtin_memcpy(&aF[mi], &As[(wm + mi * 16 + fr) * 64 + so], 16);
#pragma unroll
      for (int ni = 0; ni < 4; ++ni)
        __builtin_memcpy(&bF[ni], &Bs[(wn + ni * 16 + fr) * 64 + so], 16);
#pragma unroll
      for (int mi = 0; mi < 4; ++mi)
#pragma unroll
        for (int ni = 0; ni < 4; ++ni)
          acc[mi][ni] = __builtin_amdgcn_mfma_f32_16x16x32_bf16(aF[mi], bF[ni], acc[mi][ni], 0, 0, 0);
    }
  }
  const int rq = (lane >> 4) * 4;
  const int cq = lane & 15;
#pragma unroll
  for (int mi = 0; mi < 4; ++mi) {
#pragma unroll
    for (int ni = 0; ni < 4; ++ni) {
      int col = n0 + wn + ni * 16 + cq;
      float bs = bias[col];
#pragma unroll
      for (int i = 0; i < 4; ++i) {
        int row = m0 + wm + mi * 16 + rq + i;
        C[(size_t)row * N + col] = acc[mi][ni][i] + bs;
      }
    }
  }
}

// ---------------- causal flash attention, S^T orientation ----------------
// Grid: 512 blocks, 1-D; head-cluster remap (bh%8 == bid%8) keeps each head's
// K/V on one XCD L2. K is DOUBLE-BUFFERED: K(t+1) is DMA'd during iter t and
// waited with counted vmcnt(8) (= V(t) 4 + K(t+1) 4 newer loads), so K latency
// is off the critical path. V stays single-buffered; its wait (vmcnt(4)) hides
// under QK+softmax. Top barrier is raw s_barrier (NOT __syncthreads -- that
// would emit vmcnt(0) and drain the prefetch). Safety: each wave's ds_read
// results are consumed by MFMAs before the barrier (lgkmcnt-enforced); Ps rows
// are wave-private; DMA-vs-read hazards are barrier-separated.
__global__ __launch_bounds__(256, 2) void attn_flash(
    const u16* __restrict__ qh, const u16* __restrict__ kh,
    const u16* __restrict__ vhT, u16* __restrict__ oh) {
  __shared__ __align__(16) u16 Ks[2][64 * 128];  // 32 KB (double-buffered)
  __shared__ __align__(16) u16 Vt[128 * 64];     // 16 KB
  __shared__ __align__(16) u16 Ps[128 * 72];     // 18 KB
  const int tid = threadIdx.x;
  const int lane = tid & 63;
  const int w = tid >> 6;
  const int cq = lane & 15;
  const int g = lane >> 4;
  const int bid = blockIdx.x;        // 0..511
  const int j = bid >> 3;            // 0..63
  const int bh = (bid & 7) + (j & 3) * 8;  // head cluster: bh%8 == bid%8
  const int p = j >> 2;              // 0..15
  const int b = bh >> 4, h = bh & 15;
  const int ktiles = 32 - p;
  int q0s[2];
  q0s[0] = p * 64;
  q0s[1] = (31 - p) * 64;

  const int krl = lane >> 4;
  const int kcl = lane & 15;
  const int vrl = lane >> 3;
  const int vcl = lane & 7;

  auto stageK = [&](int kt, int bufi) {
    const size_t kvb = (size_t)bh * 2048 + (size_t)kt * 64;
#pragma unroll
    for (int i = 0; i < 4; ++i) {
      int row = w * 16 + i * 4 + krl;
      int cgl = kcl ^ (row & 7);
      const char* src = (const char*)(kh + (kvb + row) * 128 + cgl * 8);
      __builtin_amdgcn_global_load_lds(
          (__attribute__((address_space(1))) void*)src,
          (__attribute__((address_space(3))) void*)(&Ks[bufi][(w * 16 + i * 4) * 128]),
          16, 0, 0);
    }
  };
  auto stageV = [&](int kt) {
#pragma unroll
    for (int i = 0; i < 4; ++i) {
      int row = w * 32 + i * 8 + vrl;
      int cgl = vcl ^ (row & 7);
      const char* src =
          (const char*)(vhT + ((size_t)bh * 128 + row) * 2048 + kt * 64 + cgl * 8);
      __builtin_amdgcn_global_load_lds(
          (__attribute__((address_space(1))) void*)src,
          (__attribute__((address_space(3))) void*)(&Vt[(w * 32 + i * 8) * 64]),
          16, 0, 0);
    }
  };

  // prologue: K(0) in flight before anything else
  stageK(0, 0);

  bf16x8 qf[2][4];
#pragma unroll
  for (int s = 0; s < 2; ++s) {
    const u16* qp = qh + ((size_t)bh * 2048 + q0s[s] + w * 16 + cq) * 128 + g * 8;
#pragma unroll
    for (int ks = 0; ks < 4; ++ks)
      __builtin_memcpy(&qf[s][ks], qp + ks * 32, 16);
  }

  f32x4 o[2][8] = {};
  float mrow[2] = {-1e30f, -1e30f};
  float lrow[2] = {0.0f, 0.0f};

  for (int kt = 0; kt < ktiles; ++kt) {
    const int cur = kt & 1;
    const bool more = (kt + 1 < ktiles);
    // top barrier: PV(t-1) done with Vt, QK(t-1) done with Ks[cur^1].
    // Raw s_barrier (no vmcnt drain) so K(t) prefetch stays in flight.
    __builtin_amdgcn_s_barrier();
    __builtin_amdgcn_sched_barrier(0);
    stageV(kt);
    if (more) {
      stageK(kt + 1, cur ^ 1);
      asm volatile("s_waitcnt vmcnt(8)" ::: "memory");  // K(kt) landed
    } else {
      asm volatile("s_waitcnt vmcnt(4)" ::: "memory");  // K(kt) landed (no K-next)
    }
    __builtin_amdgcn_s_barrier();
    __builtin_amdgcn_sched_barrier(0);

    const bool nA = (kt <= p);
    f32x4 S[4][2] = {};
    __builtin_amdgcn_s_setprio(1);
#pragma unroll
    for (int ks = 0; ks < 4; ++ks) {
#pragma unroll
      for (int mt = 0; mt < 4; ++mt) {
        bf16x8 kf;
        int slot = (ks * 4 + g) ^ (cq & 7);
        __builtin_memcpy(&kf, &Ks[cur][(mt * 16 + cq) * 128 + slot * 8], 16);
        if (nA)
          S[mt][0] = __builtin_amdgcn_mfma_f32_16x16x32_bf16(kf, qf[0][ks], S[mt][0], 0, 0, 0);
        S[mt][1] = __builtin_amdgcn_mfma_f32_16x16x32_bf16(kf, qf[1][ks], S[mt][1], 0, 0, 0);
      }
    }
    __builtin_amdgcn_s_setprio(0);

#pragma unroll
    for (int s = 0; s < 2; ++s) {
      if (s == 0 && !nA) continue;
      const int dtile = s ? (ktiles - 1) : p;
      if (kt == dtile) {
        const int qg = q0s[s] + w * 16 + cq;
#pragma unroll
        for (int mt = 0; mt < 4; ++mt)
#pragma unroll
          for (int i = 0; i < 4; ++i)
            if (kt * 64 + mt * 16 + g * 4 + i > qg) S[mt][s][i] = -1e30f;
      }
      float mx = S[0][s][0];
#pragma unroll
      for (int mt = 0; mt < 4; ++mt)
#pragma unroll
        for (int i = 0; i < 4; ++i) mx = fmaxf(mx, S[mt][s][i]);
      mx = fmaxf(mx, __shfl_xor(mx, 16));
      mx = fmaxf(mx, __shfl_xor(mx, 32));
      float mnew = fmaxf(mrow[s], mx);
      float al = __expf(mrow[s] - mnew);
      mrow[s] = mnew;
      float rs = 0.0f;
#pragma unroll
      for (int mt = 0; mt < 4; ++mt) {
        float e0 = __expf(S[mt][s][0] - mnew);
        float e1 = __expf(S[mt][s][1] - mnew);
        float e2 = __expf(S[mt][s][2] - mnew);
        float e3 = __expf(S[mt][s][3] - mnew);
        rs += (e0 + e1) + (e2 + e3);
        ushort4 pk;
        pk.x = f2b(e0); pk.y = f2b(e1); pk.z = f2b(e2); pk.w = f2b(e3);
        *(ushort4*)&Ps[(s * 64 + w * 16 + cq) * 72 + mt * 16 + g * 4] = pk;
      }
      rs += __shfl_xor(rs, 16);
      rs += __shfl_xor(rs, 32);
      lrow[s] = lrow[s] * al + rs;
#pragma unroll
      for (int dmt = 0; dmt < 8; ++dmt) {
        o[s][dmt][0] *= al; o[s][dmt][1] *= al;
        o[s][dmt][2] *= al; o[s][dmt][3] *= al;
      }
    }

    // V(kt) fully landed in Vt before PV reads it (K(t+1) may stay in flight)
    if (more) asm volatile("s_waitcnt vmcnt(4)" ::: "memory");
    else      asm volatile("s_waitcnt vmcnt(0)" ::: "memory");
    __builtin_amdgcn_s_barrier();
    __builtin_amdgcn_sched_barrier(0);

    __builtin_amdgcn_s_setprio(1);
#pragma unroll
    for (int ks = 0; ks < 2; ++ks) {
      bf16x8 pf0, pf1;
      if (nA) __builtin_memcpy(&pf0, &Ps[(w * 16 + cq) * 72 + ks * 32 + g * 8], 16);
      __builtin_memcpy(&pf1, &Ps[(64 + w * 16 + cq) * 72 + ks * 32 + g * 8], 16);
#pragma unroll
      for (int dmt = 0; dmt < 8; ++dmt) {
        bf16x8 vf;
        int slot = (ks * 4 + g) ^ (cq & 7);
        __builtin_memcpy(&vf, &Vt[(dmt * 16 + cq) * 64 + slot * 8], 16);
        if (nA)
          o[0][dmt] = __builtin_amdgcn_mfma_f32_16x16x32_bf16(vf, pf0, o[0][dmt], 0, 0, 0);
        o[1][dmt] = __builtin_amdgcn_mfma_f32_16x16x32_bf16(vf, pf1, o[1][dmt], 0, 0, 0);
      }
    }
    __builtin_amdgcn_s_setprio(0);
  }

#pragma unroll
  for (int s = 0; s < 2; ++s) {
    float inv = 1.0f / lrow[s];
    int qg = q0s[s] + w * 16 + cq;
    size_t base = ((size_t)(b * 2048 + qg)) * 2048 + h * 128;
#pragma unroll
    for (int dmt = 0; dmt < 8; ++dmt) {
      ushort4 t;
      t.x = f2b(o[s][dmt][0] * inv);
      t.y = f2b(o[s][dmt][1] * inv);
      t.z = f2b(o[s][dmt][2] * inv);
      t.w = f2b(o[s][dmt][3] * inv);
      *(ushort4*)(oh + base + dmt * 16 + g * 4) = t;
    }
  }
}

extern "C" void kernel_launch(void* const* d_in, const int* in_sizes, int n_in,
                              void* d_out, int out_size, void* d_ws, size_t ws_size,
                              hipStream_t stream) {
  (void)in_sizes; (void)n_in; (void)out_size; (void)ws_size;
  const float* query = (const float*)d_in[0];
  const float* W_qkv = (const float*)d_in[1];
  const float* b_qkv = (const float*)d_in[2];
  const float* W_out = (const float*)d_in[3];
  const float* b_out = (const float*)d_in[4];
  float* out = (float*)d_out;
  char* ws = (char*)d_ws;

  u16*    Abf  = (u16*)(ws + 0);                    // 16 MB  query bf16
  u16*    W1bf = (u16*)(ws + (size_t)16777216);     // 24 MB  W_qkv bf16
  u16*    W2bf = (u16*)(ws + (size_t)41943040);     //  8 MB  W_out bf16
  u16*    qhp  = (u16*)(ws + (size_t)50331648);     // 16 MB  (B*H,L,128) pre-scaled
  u16*    khp  = (u16*)(ws + (size_t)67108864);     // 16 MB  (B*H,L,128)
  u16*    vhT  = (u16*)(ws + (size_t)83886080);     // 16 MB  (B*H,128,L)
  u16*    ohp  = (u16*)(ws + (size_t)100663296);    // 16 MB  attn out (B,L,2048)
  float2* tab  = (float2*)(ws + (size_t)117440512); //  1 MB  rope cos/sin

  convert_all<<<24576, 256, 0, stream>>>((const float4*)query, (const float4*)W_qkv,
                                         (const float4*)W_out, (ushort4*)ws);
  rope_tab<<<512, 256, 0, stream>>>(tab);
  gemm_qkv<<<dim3(48, 32), 256, 0, stream>>>(Abf, W1bf, b_qkv, tab, qhp, khp, vhT);
  attn_flash<<<dim3(512), 256, 0, stream>>>(qhp, khp, vhT, ohp);
  gemm_bt<<<dim3(16, 32), 256, 0, stream>>>(ohp, W2bf, b_out, out, 4096, 2048, 2048);
}

// Round 5
// 378.840 us; speedup vs baseline: 1.0186x; 1.0186x over previous
//
#include <hip/hip_runtime.h>

typedef unsigned short u16;
typedef unsigned int u32;
typedef __bf16 bf16x8 __attribute__((ext_vector_type(8)));
typedef float f32x4 __attribute__((ext_vector_type(4)));

__device__ __forceinline__ u16 f2b(float f) {
  u32 u = __float_as_uint(f);
  u32 r = (u + 0x7fffu + ((u >> 16) & 1u)) >> 16;
  return (u16)r;
}
__device__ __forceinline__ float b2f(u16 v) {
  return __uint_as_float(((u32)v) << 16);
}

// ---------------- fused fp32 -> bf16 cast of query, W_qkv, W_out ----------------
__global__ __launch_bounds__(256) void convert_all(
    const float4* __restrict__ q, const float4* __restrict__ w1,
    const float4* __restrict__ w2, ushort4* __restrict__ out) {
  int i = blockIdx.x * 256 + threadIdx.x;  // < 6291456
  float4 f;
  if (i < 2097152) f = q[i];
  else if (i < 5242880) f = w1[i - 2097152];
  else f = w2[i - 5242880];
  ushort4 o;
  o.x = f2b(f.x); o.y = f2b(f.y); o.z = f2b(f.z); o.w = f2b(f.w);
  out[i] = o;
}

// ---------------- RoPE cos/sin table: tab[l*64+dp] = (cos, sin) ----------------
__global__ __launch_bounds__(256) void rope_tab(float2* __restrict__ tab) {
  int idx = blockIdx.x * 256 + threadIdx.x;  // 131072 = 2048*64
  int l = idx >> 6, dp = idx & 63;
  float inv = exp2f(-(float)dp * 0.20762050593046869f);  // log2(10000)/64
  float ang = (float)l * inv;
  float s, c;
  sincosf(ang, &s, &c);
  tab[idx] = make_float2(c, s);
}

// ---------------- GEMM1 + fused RoPE/head-split/V-transpose epilogue ----------
// Known-good structure (141 us, 730 TF): 128x128 tile, 4 blocks/CU TLP.
__global__ __launch_bounds__(256) void gemm_qkv(
    const u16* __restrict__ A, const u16* __restrict__ B,
    const float* __restrict__ bias, const float2* __restrict__ tab,
    u16* __restrict__ qh, u16* __restrict__ kh, u16* __restrict__ vhT) {
  __shared__ __align__(16) u16 sh[16512];  // As(8192) | Bs(8192); epi: T stride 129
  u16* As = sh;
  u16* Bs = sh + 8192;
  const int K = 2048;
  const int tid = threadIdx.x;
  const int lane = tid & 63;
  const int wave = tid >> 6;
  const int m0 = blockIdx.y * 128;
  const int n0 = blockIdx.x * 128;
  const int wm = (wave & 1) * 64;
  const int wn = (wave >> 1) * 64;
  f32x4 acc[4][4] = {};

  const int srow = wave * 32 + (lane >> 3);
  const int scb = ((lane & 7) ^ (lane >> 3)) * 16;
  const int fr = lane & 15;
  const int g = lane >> 4;

  for (int kt = 0; kt < 32; ++kt) {
    const int k0 = kt << 6;
    __syncthreads();
    {
      const char* gA = (const char*)A + ((size_t)(m0 + srow) * K + k0) * 2 + scb;
      const char* gB = (const char*)B + ((size_t)(n0 + srow) * K + k0) * 2 + scb;
#pragma unroll
      for (int i = 0; i < 4; ++i) {
        __builtin_amdgcn_global_load_lds(
            (__attribute__((address_space(1))) void*)(gA + (size_t)i * 8 * K * 2),
            (__attribute__((address_space(3))) void*)(As + (wave * 32 + i * 8) * 64),
            16, 0, 0);
        __builtin_amdgcn_global_load_lds(
            (__attribute__((address_space(1))) void*)(gB + (size_t)i * 8 * K * 2),
            (__attribute__((address_space(3))) void*)(Bs + (wave * 32 + i * 8) * 64),
            16, 0, 0);
      }
    }
    __syncthreads();
#pragma unroll
    for (int ks = 0; ks < 2; ++ks) {
      const int so = ((ks * 4 + g) ^ (fr & 7)) * 8;
      bf16x8 aF[4], bF[4];
#pragma unroll
      for (int mi = 0; mi < 4; ++mi)
        __builtin_memcpy(&aF[mi], &As[(wm + mi * 16 + fr) * 64 + so], 16);
#pragma unroll
      for (int ni = 0; ni < 4; ++ni)
        __builtin_memcpy(&bF[ni], &Bs[(wn + ni * 16 + fr) * 64 + so], 16);
#pragma unroll
      for (int mi = 0; mi < 4; ++mi)
#pragma unroll
        for (int ni = 0; ni < 4; ++ni)
          acc[mi][ni] = __builtin_amdgcn_mfma_f32_16x16x32_bf16(aF[mi], bF[ni], acc[mi][ni], 0, 0, 0);
    }
  }

  // ---- epilogue: acc -> LDS tile T (bf16, stride 129) ----
  __syncthreads();  // all waves done reading As/Bs before overwrite
  const int rq = (lane >> 4) * 4;
  const int cq = lane & 15;
#pragma unroll
  for (int mi = 0; mi < 4; ++mi) {
#pragma unroll
    for (int ni = 0; ni < 4; ++ni) {
      int c = wn + ni * 16 + cq;
      float bs = bias[n0 + c];
#pragma unroll
      for (int i = 0; i < 4; ++i) {
        int r = wm + mi * 16 + rq + i;
        sh[r * 129 + c] = f2b(acc[mi][ni][i] + bs);
      }
    }
  }
  __syncthreads();

  const int t = n0 >> 7;       // 0..47
  const int h = t & 15;
  const int bq = m0 >> 11;     // batch (M = B*L, 2048 each)
  const int l0 = m0 & 2047;
  const int bh = bq * 16 + h;

  if (t < 32) {
    // q or k head tile: RoPE rows. 128 rows x 64 pairs, 32 iters.
    const float qs = (t < 16) ? 0.08838834764831845f : 1.0f;
    u16* dst = (t < 16) ? qh : kh;
#pragma unroll 4
    for (int it = 0; it < 32; ++it) {
      int idx = it * 256 + tid;
      int l = idx >> 6, dp = idx & 63;
      float2 cs = tab[(size_t)(l0 + l) * 64 + dp];
      float x1 = b2f(sh[l * 129 + dp]);
      float x2 = b2f(sh[l * 129 + dp + 64]);
      size_t o = ((size_t)bh * 2048 + l0 + l) * 128;
      dst[o + dp]      = f2b((x1 * cs.x - x2 * cs.y) * qs);
      dst[o + dp + 64] = f2b((x2 * cs.x + x1 * cs.y) * qs);
    }
  } else {
    // v head tile: transposed store vhT[bh*128+d][l]. 128 d x 64 l-pairs.
#pragma unroll 4
    for (int it = 0; it < 32; ++it) {
      int idx = it * 256 + tid;
      int d = idx >> 6, l2 = (idx & 63) * 2;
      ushort2 t2;
      t2.x = sh[l2 * 129 + d];
      t2.y = sh[(l2 + 1) * 129 + d];
      *(ushort2*)(vhT + ((size_t)bh * 128 + d) * 2048 + l0 + l2) = t2;
    }
  }
}

// ---------------- GEMM2: out[M,N] = A[M,K] * B[N,K]^T + bias (fp32 out) -------
__global__ __launch_bounds__(256) void gemm_bt(
    const u16* __restrict__ A, const u16* __restrict__ B,
    const float* __restrict__ bias, float* __restrict__ C,
    int M, int N, int K) {
  __shared__ __align__(16) u16 As[128 * 64];
  __shared__ __align__(16) u16 Bs[128 * 64];
  const int tid = threadIdx.x;
  const int lane = tid & 63;
  const int wave = tid >> 6;
  const int m0 = blockIdx.y * 128;
  const int n0 = blockIdx.x * 128;
  const int wm = (wave & 1) * 64;
  const int wn = (wave >> 1) * 64;
  f32x4 acc[4][4] = {};

  const int srow = wave * 32 + (lane >> 3);
  const int scb = ((lane & 7) ^ (lane >> 3)) * 16;
  const int fr = lane & 15;
  const int g = lane >> 4;

  const int kiters = K >> 6;
  for (int kt = 0; kt < kiters; ++kt) {
    const int k0 = kt << 6;
    __syncthreads();
    {
      const char* gA = (const char*)A + ((size_t)(m0 + srow) * K + k0) * 2 + scb;
      const char* gB = (const char*)B + ((size_t)(n0 + srow) * K + k0) * 2 + scb;
#pragma unroll
      for (int i = 0; i < 4; ++i) {
        __builtin_amdgcn_global_load_lds(
            (__attribute__((address_space(1))) void*)(gA + (size_t)i * 8 * K * 2),
            (__attribute__((address_space(3))) void*)(As + (wave * 32 + i * 8) * 64),
            16, 0, 0);
        __builtin_amdgcn_global_load_lds(
            (__attribute__((address_space(1))) void*)(gB + (size_t)i * 8 * K * 2),
            (__attribute__((address_space(3))) void*)(Bs + (wave * 32 + i * 8) * 64),
            16, 0, 0);
      }
    }
    __syncthreads();
#pragma unroll
    for (int ks = 0; ks < 2; ++ks) {
      const int so = ((ks * 4 + g) ^ (fr & 7)) * 8;
      bf16x8 aF[4], bF[4];
#pragma unroll
      for (int mi = 0; mi < 4; ++mi)
        __builtin_memcpy(&aF[mi], &As[(wm + mi * 16 + fr) * 64 + so], 16);
#pragma unroll
      for (int ni = 0; ni < 4; ++ni)
        __builtin_memcpy(&bF[ni], &Bs[(wn + ni * 16 + fr) * 64 + so], 16);
#pragma unroll
      for (int mi = 0; mi < 4; ++mi)
#pragma unroll
        for (int ni = 0; ni < 4; ++ni)
          acc[mi][ni] = __builtin_amdgcn_mfma_f32_16x16x32_bf16(aF[mi], bF[ni], acc[mi][ni], 0, 0, 0);
    }
  }
  const int rq = (lane >> 4) * 4;
  const int cq = lane & 15;
#pragma unroll
  for (int mi = 0; mi < 4; ++mi) {
#pragma unroll
    for (int ni = 0; ni < 4; ++ni) {
      int col = n0 + wn + ni * 16 + cq;
      float bs = bias[col];
#pragma unroll
      for (int i = 0; i < 4; ++i) {
        int row = m0 + wm + mi * 16 + rq + i;
        C[(size_t)row * N + col] = acc[mi][ni][i] + bs;
      }
    }
  }
}

// ---------------- causal flash attention, S^T orientation ----------------
// Grid: 512 blocks, 1-D; head-cluster remap (bh%8 == bid%8) keeps each head's
// K/V on one XCD L2. LDS stays 50 KB -> 3 blocks/CU (round-4 lesson: 66 KB
// K-double-buffer cut residency to 2 blocks/CU and lost more TLP than the
// prefetch gained). K latency is instead hidden via REGISTER prefetch (T14):
// K(t+1) is global_load'ed into 16 VGPRs just before QK^T(t) and ds_written
// into Ks during PV(t) (after the mid barrier ensures all waves finished
// QK(t)'s Ks reads). QK(t+1) then needs no vm wait at all. V stays DMA'd;
// its vmcnt(4) wait hides under QK+softmax.
__global__ __launch_bounds__(256, 2) void attn_flash(
    const u16* __restrict__ qh, const u16* __restrict__ kh,
    const u16* __restrict__ vhT, u16* __restrict__ oh) {
  __shared__ __align__(16) u16 Ks[64 * 128];   // 16 KB
  __shared__ __align__(16) u16 Vt[128 * 64];   // 16 KB
  __shared__ __align__(16) u16 Ps[128 * 72];   // 18 KB
  const int tid = threadIdx.x;
  const int lane = tid & 63;
  const int w = tid >> 6;
  const int cq = lane & 15;
  const int g = lane >> 4;
  const int bid = blockIdx.x;        // 0..511
  const int j = bid >> 3;            // 0..63
  const int bh = (bid & 7) + (j & 3) * 8;  // head cluster: bh%8 == bid%8
  const int p = j >> 2;              // 0..15
  const int b = bh >> 4, h = bh & 15;
  const int ktiles = 32 - p;
  int q0s[2];
  q0s[0] = p * 64;
  q0s[1] = (31 - p) * 64;

  const int krl = lane >> 4;
  const int kcl = lane & 15;
  const int vrl = lane >> 3;
  const int vcl = lane & 7;

  // global source for lane's 16B of K tile kt, sub-row i (matches the LDS
  // layout global_load_lds would produce: lane's 16B at Ks_base + lane*16B)
  auto kSrc = [&](int kt, int i) -> const char* {
    int row = w * 16 + i * 4 + krl;
    int cgl = kcl ^ (row & 7);
    return (const char*)(kh + ((size_t)bh * 2048 + (size_t)kt * 64 + row) * 128 + cgl * 8);
  };
  auto stageV = [&](int kt) {
#pragma unroll
    for (int i = 0; i < 4; ++i) {
      int row = w * 32 + i * 8 + vrl;
      int cgl = vcl ^ (row & 7);
      const char* src =
          (const char*)(vhT + ((size_t)bh * 128 + row) * 2048 + kt * 64 + cgl * 8);
      __builtin_amdgcn_global_load_lds(
          (__attribute__((address_space(1))) void*)src,
          (__attribute__((address_space(3))) void*)(&Vt[(w * 32 + i * 8) * 64]),
          16, 0, 0);
    }
  };

  // prologue: K(0) via DMA into Ks (4 loads), pinned before the Q loads so the
  // vmcnt count below is exact
#pragma unroll
  for (int i = 0; i < 4; ++i)
    __builtin_amdgcn_global_load_lds(
        (__attribute__((address_space(1))) void*)kSrc(0, i),
        (__attribute__((address_space(3))) void*)(&Ks[(w * 16 + i * 4) * 128]),
        16, 0, 0);
  __builtin_amdgcn_sched_barrier(0);

  bf16x8 qf[2][4];  // 8 global loads
#pragma unroll
  for (int s = 0; s < 2; ++s) {
    const u16* qp = qh + ((size_t)bh * 2048 + q0s[s] + w * 16 + cq) * 128 + g * 8;
#pragma unroll
    for (int ks = 0; ks < 4; ++ks)
      __builtin_memcpy(&qf[s][ks], qp + ks * 32, 16);
  }

  f32x4 o[2][8] = {};
  float mrow[2] = {-1e30f, -1e30f};
  float lrow[2] = {0.0f, 0.0f};

  // outstanding: K0(4, oldest) + Q(8) -> vmcnt(8) drains K0
  asm volatile("s_waitcnt vmcnt(8)" ::: "memory");
  __builtin_amdgcn_s_barrier();
  __builtin_amdgcn_sched_barrier(0);

  for (int kt = 0; kt < ktiles; ++kt) {
    const bool more = (kt + 1 < ktiles);
    // top of iter: Ks holds K(kt) (DMA for kt=0, ds_write from prev iter else)
    stageV(kt);                     // 4 DMA (Vt reads of prev iter done: end barrier)
    bf16x8 kreg[4];
    if (more) {
#pragma unroll
      for (int i = 0; i < 4; ++i)
        __builtin_memcpy(&kreg[i], kSrc(kt + 1, i), 16);  // 4 reg loads
    }
    __builtin_amdgcn_sched_barrier(0);  // pin issues above QK

    const bool nA = (kt <= p);
    f32x4 S[4][2] = {};
    __builtin_amdgcn_s_setprio(1);
#pragma unroll
    for (int ks = 0; ks < 4; ++ks) {
#pragma unroll
      for (int mt = 0; mt < 4; ++mt) {
        bf16x8 kf;
        int slot = (ks * 4 + g) ^ (cq & 7);
        __builtin_memcpy(&kf, &Ks[(mt * 16 + cq) * 128 + slot * 8], 16);
        if (nA)
          S[mt][0] = __builtin_amdgcn_mfma_f32_16x16x32_bf16(kf, qf[0][ks], S[mt][0], 0, 0, 0);
        S[mt][1] = __builtin_amdgcn_mfma_f32_16x16x32_bf16(kf, qf[1][ks], S[mt][1], 0, 0, 0);
      }
    }
    __builtin_amdgcn_s_setprio(0);

#pragma unroll
    for (int s = 0; s < 2; ++s) {
      if (s == 0 && !nA) continue;
      const int dtile = s ? (ktiles - 1) : p;
      if (kt == dtile) {
        const int qg = q0s[s] + w * 16 + cq;
#pragma unroll
        for (int mt = 0; mt < 4; ++mt)
#pragma unroll
          for (int i = 0; i < 4; ++i)
            if (kt * 64 + mt * 16 + g * 4 + i > qg) S[mt][s][i] = -1e30f;
      }
      float mx = S[0][s][0];
#pragma unroll
      for (int mt = 0; mt < 4; ++mt)
#pragma unroll
        for (int i = 0; i < 4; ++i) mx = fmaxf(mx, S[mt][s][i]);
      mx = fmaxf(mx, __shfl_xor(mx, 16));
      mx = fmaxf(mx, __shfl_xor(mx, 32));
      float mnew = fmaxf(mrow[s], mx);
      float al = __expf(mrow[s] - mnew);
      mrow[s] = mnew;
      float rs = 0.0f;
#pragma unroll
      for (int mt = 0; mt < 4; ++mt) {
        float e0 = __expf(S[mt][s][0] - mnew);
        float e1 = __expf(S[mt][s][1] - mnew);
        float e2 = __expf(S[mt][s][2] - mnew);
        float e3 = __expf(S[mt][s][3] - mnew);
        rs += (e0 + e1) + (e2 + e3);
        ushort4 pk;
        pk.x = f2b(e0); pk.y = f2b(e1); pk.z = f2b(e2); pk.w = f2b(e3);
        *(ushort4*)&Ps[(s * 64 + w * 16 + cq) * 72 + mt * 16 + g * 4] = pk;
      }
      rs += __shfl_xor(rs, 16);
      rs += __shfl_xor(rs, 32);
      lrow[s] = lrow[s] * al + rs;
#pragma unroll
      for (int dmt = 0; dmt < 8; ++dmt) {
        o[s][dmt][0] *= al; o[s][dmt][1] *= al;
        o[s][dmt][2] *= al; o[s][dmt][3] *= al;
      }
    }

    // drain V (oldest 4); kregs (newest 4) may stay in flight
    if (more) asm volatile("s_waitcnt vmcnt(4)" ::: "memory");
    else      asm volatile("s_waitcnt vmcnt(0)" ::: "memory");
    __builtin_amdgcn_s_barrier();   // all waves: QK(kt) Ks-reads done; Vt full
    __builtin_amdgcn_sched_barrier(0);

    if (more) {
      asm volatile("s_waitcnt vmcnt(0)" ::: "memory");  // kregs landed
      __builtin_amdgcn_sched_barrier(0);
#pragma unroll
      for (int i = 0; i < 4; ++i)
        *(bf16x8*)&Ks[(w * 16 + i * 4) * 128 + lane * 8] = kreg[i];  // ds_write_b128
    }

    __builtin_amdgcn_s_setprio(1);
#pragma unroll
    for (int ks = 0; ks < 2; ++ks) {
      bf16x8 pf0, pf1;
      if (nA) __builtin_memcpy(&pf0, &Ps[(w * 16 + cq) * 72 + ks * 32 + g * 8], 16);
      __builtin_memcpy(&pf1, &Ps[(64 + w * 16 + cq) * 72 + ks * 32 + g * 8], 16);
#pragma unroll
      for (int dmt = 0; dmt < 8; ++dmt) {
        bf16x8 vf;
        int slot = (ks * 4 + g) ^ (cq & 7);
        __builtin_memcpy(&vf, &Vt[(dmt * 16 + cq) * 64 + slot * 8], 16);
        if (nA)
          o[0][dmt] = __builtin_amdgcn_mfma_f32_16x16x32_bf16(vf, pf0, o[0][dmt], 0, 0, 0);
        o[1][dmt] = __builtin_amdgcn_mfma_f32_16x16x32_bf16(vf, pf1, o[1][dmt], 0, 0, 0);
      }
    }
    __builtin_amdgcn_s_setprio(0);

    // drain ds_writes of K(kt+1) so next iter's QK sees them after the barrier
    asm volatile("s_waitcnt lgkmcnt(0)" ::: "memory");
    __builtin_amdgcn_s_barrier();
    __builtin_amdgcn_sched_barrier(0);
  }

#pragma unroll
  for (int s = 0; s < 2; ++s) {
    float inv = 1.0f / lrow[s];
    int qg = q0s[s] + w * 16 + cq;
    size_t base = ((size_t)(b * 2048 + qg)) * 2048 + h * 128;
#pragma unroll
    for (int dmt = 0; dmt < 8; ++dmt) {
      ushort4 t;
      t.x = f2b(o[s][dmt][0] * inv);
      t.y = f2b(o[s][dmt][1] * inv);
      t.z = f2b(o[s][dmt][2] * inv);
      t.w = f2b(o[s][dmt][3] * inv);
      *(ushort4*)(oh + base + dmt * 16 + g * 4) = t;
    }
  }
}

extern "C" void kernel_launch(void* const* d_in, const int* in_sizes, int n_in,
                              void* d_out, int out_size, void* d_ws, size_t ws_size,
                              hipStream_t stream) {
  (void)in_sizes; (void)n_in; (void)out_size; (void)ws_size;
  const float* query = (const float*)d_in[0];
  const float* W_qkv = (const float*)d_in[1];
  const float* b_qkv = (const float*)d_in[2];
  const float* W_out = (const float*)d_in[3];
  const float* b_out = (const float*)d_in[4];
  float* out = (float*)d_out;
  char* ws = (char*)d_ws;

  u16*    Abf  = (u16*)(ws + 0);                    // 16 MB  query bf16
  u16*    W1bf = (u16*)(ws + (size_t)16777216);     // 24 MB  W_qkv bf16
  u16*    W2bf = (u16*)(ws + (size_t)41943040);     //  8 MB  W_out bf16
  u16*    qhp  = (u16*)(ws + (size_t)50331648);     // 16 MB  (B*H,L,128) pre-scaled
  u16*    khp  = (u16*)(ws + (size_t)67108864);     // 16 MB  (B*H,L,128)
  u16*    vhT  = (u16*)(ws + (size_t)83886080);     // 16 MB  (B*H,128,L)
  u16*    ohp  = (u16*)(ws + (size_t)100663296);    // 16 MB  attn out (B,L,2048)
  float2* tab  = (float2*)(ws + (size_t)117440512); //  1 MB  rope cos/sin

  convert_all<<<24576, 256, 0, stream>>>((const float4*)query, (const float4*)W_qkv,
                                         (const float4*)W_out, (ushort4*)ws);
  rope_tab<<<512, 256, 0, stream>>>(tab);
  gemm_qkv<<<dim3(48, 32), 256, 0, stream>>>(Abf, W1bf, b_qkv, tab, qhp, khp, vhT);
  attn_flash<<<dim3(512), 256, 0, stream>>>(qhp, khp, vhT, ohp);
  gemm_bt<<<dim3(16, 32), 256, 0, stream>>>(ohp, W2bf, b_out, out, 4096, 2048, 2048);
}